// Round 4
// baseline (225.931 us; speedup 1.0000x reference)
//
#include <hip/hip_runtime.h>

// RoiPooling (crop_and_resize, bilinear): x (1,128,128,256) f32 NHWC,
// rois (4000,4) f32 [y1,x1,y2,x2] in [0,1] -> out (4000,7,7,256) f32.
//
// R4: spatial binning for L2 locality. The 784MB gather stream has all its
// reuse ACROSS rois (~48x per pixel) but scattered across XCDs -> L2 thrash.
// Bin cells into 8 y-bands of 16 rows (2MB < 4MB per-XCD L2); pass-2 block
// bid%8 handles band bid%8 so each band becomes L2-resident on one XCD
// (round-robin dispatch heuristic; correctness independent of mapping).

typedef float v4f __attribute__((ext_vector_type(4)));

constexpr int H = 128, W = 128, C = 256;
constexpr int PH = 7, PW = 7;
constexpr int NROI = 4000;
constexpr int NCELL = NROI * PH * PW;            // 196000
constexpr int BANDS = 8;
constexpr int BAND_SHIFT = 4;                    // 16 rows/band = 2MB
constexpr int G_PER_BUCKET = 512;
constexpr int P2_BLOCKS = BANDS * G_PER_BUCKET;  // 4096
constexpr size_t WS_INTS = (size_t)BANDS + (size_t)BANDS * NCELL;

__global__ __launch_bounds__(64) void zero_counts(int* cnt) {
    if (threadIdx.x < BANDS) cnt[threadIdx.x] = 0;
}

__global__ __launch_bounds__(256) void bin_cells(const float* __restrict__ rois,
                                                 int* __restrict__ cnt,
                                                 int* __restrict__ lists)
{
    const int cell = blockIdx.x * 256 + threadIdx.x;
    const int lane = threadIdx.x & 63;
    const bool active = cell < NCELL;
    int band = 0;
    if (active) {
        const int r  = cell / (PH * PW);
        const int pq = cell - r * (PH * PW);
        const int iy = pq / PW;
        const float y1 = rois[r * 4 + 0];
        const float y2 = rois[r * 4 + 2];
        const float ys = y1 * (float)(H - 1) + (float)iy * ((y2 - y1) * (float)(H - 1) / (float)(PH - 1));
        int y0 = (int)floorf(ys);
        y0 = min(max(y0, 0), H - 1);
        band = y0 >> BAND_SHIFT;
    }
    // Wave-aggregated bucket append (8 atomics per wave instead of 64).
#pragma unroll
    for (int b = 0; b < BANDS; ++b) {
        const unsigned long long m = __ballot(active && band == b);
        if (active && band == b) {
            const int leader = __ffsll(m) - 1;
            const int total  = __popcll(m);
            const int pre    = __popcll(m & ((1ull << lane) - 1ull));
            int base = 0;
            if (lane == leader) base = atomicAdd(&cnt[b], total);
            base = __shfl(base, leader);
            lists[(size_t)b * NCELL + base + pre] = cell;
        }
    }
}

__device__ __forceinline__ void cell_geom(const float* __restrict__ rois, int cell,
                                          unsigned& b00, unsigned& b01,
                                          unsigned& b10, unsigned& b11,
                                          float& wy, float& wx, bool& valid)
{
    const int r  = cell / (PH * PW);
    const int pq = cell - r * (PH * PW);
    const int iy = pq / PW;
    const int ix = pq - iy * PW;

    const float y1 = rois[r * 4 + 0];
    const float x1 = rois[r * 4 + 1];
    const float y2 = rois[r * 4 + 2];
    const float x2 = rois[r * 4 + 3];

    // Match reference order exactly.
    const float ys = y1 * (float)(H - 1) + (float)iy * ((y2 - y1) * (float)(H - 1) / (float)(PH - 1));
    const float xs = x1 * (float)(W - 1) + (float)ix * ((x2 - x1) * (float)(W - 1) / (float)(PW - 1));

    const float y0f = floorf(ys);
    const float x0f = floorf(xs);
    wy = ys - y0f;
    wx = xs - x0f;

    int y0  = (int)y0f; y0  = min(max(y0, 0), H - 1);
    int y1i = min(y0 + 1, H - 1);
    int x0  = (int)x0f; x0  = min(max(x0, 0), W - 1);
    int x1i = min(x0 + 1, W - 1);

    valid = (ys >= 0.0f) & (ys <= (float)(H - 1)) &
            (xs >= 0.0f) & (xs <= (float)(W - 1));

    b00 = ((unsigned)(y0  * W + x0 )) * C;
    b01 = ((unsigned)(y0  * W + x1i)) * C;
    b10 = ((unsigned)(y1i * W + x0 )) * C;
    b11 = ((unsigned)(y1i * W + x1i)) * C;
}

__global__ __launch_bounds__(256) void roi_pool_binned(
    const float* __restrict__ x, const float* __restrict__ rois,
    float* __restrict__ out, const int* __restrict__ cnt,
    const int* __restrict__ lists)
{
    const int bucket = blockIdx.x & (BANDS - 1);   // heuristic: == XCD id
    const int group  = blockIdx.x >> 3;
    const int n = cnt[bucket];
    const int* __restrict__ list = lists + (size_t)bucket * NCELL;
    const int wave = threadIdx.x >> 6;
    const int lane = threadIdx.x & 63;
    const unsigned c4 = (unsigned)lane * 4u;

    for (int base0 = group * 8; base0 < n; base0 += G_PER_BUCKET * 8) {
        int cells[2]; bool live[2], validv[2];
        float wxv[2], wyv[2];
        v4f a[2], b[2], c[2], d[2];
#pragma unroll
        for (int k = 0; k < 2; ++k) {
            const int i = base0 + wave * 2 + k;
            live[k] = (i < n);
            const int cell = live[k] ? list[i] : 0;
            cells[k] = cell;
            unsigned b00, b01, b10, b11;
            cell_geom(rois, cell, b00, b01, b10, b11, wyv[k], wxv[k], validv[k]);
            if (live[k]) {
                a[k] = *(const v4f*)(x + b00 + c4);
                b[k] = *(const v4f*)(x + b01 + c4);
                c[k] = *(const v4f*)(x + b10 + c4);
                d[k] = *(const v4f*)(x + b11 + c4);
            }
        }
#pragma unroll
        for (int k = 0; k < 2; ++k) {
            if (!live[k]) continue;
            const float wx = wxv[k], wy = wyv[k];
            const v4f top = a[k] * (1.0f - wx) + b[k] * wx;
            const v4f bot = c[k] * (1.0f - wx) + d[k] * wx;
            v4f res = top * (1.0f - wy) + bot * wy;
            if (!validv[k]) res = (v4f)0.0f;
            v4f* o = (v4f*)(out + (unsigned)cells[k] * C + c4);
            __builtin_nontemporal_store(res, o);
        }
    }
}

// Fallback (ws too small): the R3 direct kernel.
__global__ __launch_bounds__(256) void roi_pool_plain(
    const float* __restrict__ x, const float* __restrict__ rois,
    float* __restrict__ out)
{
    const int wave = threadIdx.x >> 6;
    const int lane = threadIdx.x & 63;
    const int cell0 = (blockIdx.x * 4 + wave) * 2;
    const unsigned c4 = (unsigned)lane * 4u;

    v4f a[2], b[2], c[2], d[2];
    float wxv[2], wyv[2]; bool validv[2];
#pragma unroll
    for (int k = 0; k < 2; ++k) {
        unsigned b00, b01, b10, b11;
        cell_geom(rois, cell0 + k, b00, b01, b10, b11, wyv[k], wxv[k], validv[k]);
        a[k] = *(const v4f*)(x + b00 + c4);
        b[k] = *(const v4f*)(x + b01 + c4);
        c[k] = *(const v4f*)(x + b10 + c4);
        d[k] = *(const v4f*)(x + b11 + c4);
    }
#pragma unroll
    for (int k = 0; k < 2; ++k) {
        const float wx = wxv[k], wy = wyv[k];
        const v4f top = a[k] * (1.0f - wx) + b[k] * wx;
        const v4f bot = c[k] * (1.0f - wx) + d[k] * wx;
        v4f res = top * (1.0f - wy) + bot * wy;
        if (!validv[k]) res = (v4f)0.0f;
        v4f* o = (v4f*)(out + (unsigned)(cell0 + k) * C + c4);
        __builtin_nontemporal_store(res, o);
    }
}

extern "C" void kernel_launch(void* const* d_in, const int* in_sizes, int n_in,
                              void* d_out, int out_size, void* d_ws, size_t ws_size,
                              hipStream_t stream)
{
    const float* x    = (const float*)d_in[0];
    const float* rois = (const float*)d_in[1];
    float* out = (float*)d_out;

    const size_t needed = WS_INTS * sizeof(int);
    if (ws_size >= needed) {
        int* cnt   = (int*)d_ws;
        int* lists = cnt + BANDS;
        zero_counts<<<1, 64, 0, stream>>>(cnt);
        bin_cells<<<(NCELL + 255) / 256, 256, 0, stream>>>(rois, cnt, lists);
        roi_pool_binned<<<P2_BLOCKS, 256, 0, stream>>>(x, rois, out, cnt, lists);
    } else {
        roi_pool_plain<<<NCELL / 8, 256, 0, stream>>>(x, rois, out);
    }
}

// Round 5
// 74.230 us; speedup vs baseline: 3.0437x; 3.0437x over previous
//
#include <hip/hip_runtime.h>

// RoiPooling (crop_and_resize, bilinear): x (1,128,128,256) f32 NHWC,
// rois (4000,4) f32 [y1,x1,y2,x2] in [0,1] -> out (4000,7,7,256) f32.
//
// R5: R4's banded pool pass (unchanged, ~61us) + fixed binning pass.
// R4's bin_cells was 162us: 24.5k device atomics all on ONE cache line
// (8 counters in 32B) -> cross-XCD line bouncing. Now: per-block LDS
// histogram (LDS atomics) + one global atomicAdd per (block,band) on
// counters padded 128B apart -> ~6k atomics across 8 independent lines.

typedef float v4f __attribute__((ext_vector_type(4)));

constexpr int H = 128, W = 128, C = 256;
constexpr int PH = 7, PW = 7;
constexpr int NROI = 4000;
constexpr int NCELL = NROI * PH * PW;            // 196000
constexpr int BANDS = 8;
constexpr int BAND_SHIFT = 4;                    // 16 rows/band = 2MB
constexpr int CNT_STRIDE = 32;                   // ints; 128B between counters
constexpr int G_PER_BUCKET = 512;
constexpr int P2_BLOCKS = BANDS * G_PER_BUCKET;  // 4096
constexpr size_t WS_INTS = (size_t)BANDS * CNT_STRIDE + (size_t)BANDS * NCELL;

__global__ __launch_bounds__(256) void zero_counts(int* cnt) {
    if (threadIdx.x < BANDS * CNT_STRIDE) cnt[threadIdx.x] = 0;
}

__global__ __launch_bounds__(256) void bin_cells(const float* __restrict__ rois,
                                                 int* __restrict__ cnt,
                                                 int* __restrict__ lists)
{
    __shared__ int lcnt[BANDS];
    __shared__ int lbase[BANDS];

    if (threadIdx.x < BANDS) lcnt[threadIdx.x] = 0;
    __syncthreads();

    const int cell = blockIdx.x * 256 + threadIdx.x;
    const bool active = cell < NCELL;
    int band = 0, myidx = 0;
    if (active) {
        const int r  = cell / (PH * PW);
        const int pq = cell - r * (PH * PW);
        const int iy = pq / PW;
        const float y1 = rois[r * 4 + 0];
        const float y2 = rois[r * 4 + 2];
        const float ys = y1 * (float)(H - 1) + (float)iy * ((y2 - y1) * (float)(H - 1) / (float)(PH - 1));
        int y0 = (int)floorf(ys);
        y0 = min(max(y0, 0), H - 1);
        band = y0 >> BAND_SHIFT;
        myidx = atomicAdd(&lcnt[band], 1);   // LDS atomic
    }
    __syncthreads();
    if (threadIdx.x < BANDS) {
        const int n = lcnt[threadIdx.x];
        lbase[threadIdx.x] = n ? atomicAdd(&cnt[threadIdx.x * CNT_STRIDE], n) : 0;
    }
    __syncthreads();
    if (active) {
        lists[(size_t)band * NCELL + lbase[band] + myidx] = cell;
    }
}

__device__ __forceinline__ void cell_geom(const float* __restrict__ rois, int cell,
                                          unsigned& b00, unsigned& b01,
                                          unsigned& b10, unsigned& b11,
                                          float& wy, float& wx, bool& valid)
{
    const int r  = cell / (PH * PW);
    const int pq = cell - r * (PH * PW);
    const int iy = pq / PW;
    const int ix = pq - iy * PW;

    const float y1 = rois[r * 4 + 0];
    const float x1 = rois[r * 4 + 1];
    const float y2 = rois[r * 4 + 2];
    const float x2 = rois[r * 4 + 3];

    // Match reference order exactly.
    const float ys = y1 * (float)(H - 1) + (float)iy * ((y2 - y1) * (float)(H - 1) / (float)(PH - 1));
    const float xs = x1 * (float)(W - 1) + (float)ix * ((x2 - x1) * (float)(W - 1) / (float)(PW - 1));

    const float y0f = floorf(ys);
    const float x0f = floorf(xs);
    wy = ys - y0f;
    wx = xs - x0f;

    int y0  = (int)y0f; y0  = min(max(y0, 0), H - 1);
    int y1i = min(y0 + 1, H - 1);
    int x0  = (int)x0f; x0  = min(max(x0, 0), W - 1);
    int x1i = min(x0 + 1, W - 1);

    valid = (ys >= 0.0f) & (ys <= (float)(H - 1)) &
            (xs >= 0.0f) & (xs <= (float)(W - 1));

    b00 = ((unsigned)(y0  * W + x0 )) * C;
    b01 = ((unsigned)(y0  * W + x1i)) * C;
    b10 = ((unsigned)(y1i * W + x0 )) * C;
    b11 = ((unsigned)(y1i * W + x1i)) * C;
}

__global__ __launch_bounds__(256) void roi_pool_binned(
    const float* __restrict__ x, const float* __restrict__ rois,
    float* __restrict__ out, const int* __restrict__ cnt,
    const int* __restrict__ lists)
{
    const int bucket = blockIdx.x & (BANDS - 1);   // heuristic: == XCD id
    const int group  = blockIdx.x >> 3;
    const int n = cnt[bucket * CNT_STRIDE];
    const int* __restrict__ list = lists + (size_t)bucket * NCELL;
    const int wave = threadIdx.x >> 6;
    const int lane = threadIdx.x & 63;
    const unsigned c4 = (unsigned)lane * 4u;

    for (int base0 = group * 8; base0 < n; base0 += G_PER_BUCKET * 8) {
        int cells[2]; bool live[2], validv[2];
        float wxv[2], wyv[2];
        v4f a[2], b[2], c[2], d[2];
#pragma unroll
        for (int k = 0; k < 2; ++k) {
            const int i = base0 + wave * 2 + k;
            live[k] = (i < n);
            const int cell = live[k] ? list[i] : 0;
            cells[k] = cell;
            unsigned b00, b01, b10, b11;
            cell_geom(rois, cell, b00, b01, b10, b11, wyv[k], wxv[k], validv[k]);
            if (live[k]) {
                a[k] = *(const v4f*)(x + b00 + c4);
                b[k] = *(const v4f*)(x + b01 + c4);
                c[k] = *(const v4f*)(x + b10 + c4);
                d[k] = *(const v4f*)(x + b11 + c4);
            }
        }
#pragma unroll
        for (int k = 0; k < 2; ++k) {
            if (!live[k]) continue;
            const float wx = wxv[k], wy = wyv[k];
            const v4f top = a[k] * (1.0f - wx) + b[k] * wx;
            const v4f bot = c[k] * (1.0f - wx) + d[k] * wx;
            v4f res = top * (1.0f - wy) + bot * wy;
            if (!validv[k]) res = (v4f)0.0f;
            v4f* o = (v4f*)(out + (unsigned)cells[k] * C + c4);
            __builtin_nontemporal_store(res, o);
        }
    }
}

// Fallback (ws too small): the R3 direct kernel.
__global__ __launch_bounds__(256) void roi_pool_plain(
    const float* __restrict__ x, const float* __restrict__ rois,
    float* __restrict__ out)
{
    const int wave = threadIdx.x >> 6;
    const int lane = threadIdx.x & 63;
    const int cell0 = (blockIdx.x * 4 + wave) * 2;
    const unsigned c4 = (unsigned)lane * 4u;

    v4f a[2], b[2], c[2], d[2];
    float wxv[2], wyv[2]; bool validv[2];
#pragma unroll
    for (int k = 0; k < 2; ++k) {
        unsigned b00, b01, b10, b11;
        cell_geom(rois, cell0 + k, b00, b01, b10, b11, wyv[k], wxv[k], validv[k]);
        a[k] = *(const v4f*)(x + b00 + c4);
        b[k] = *(const v4f*)(x + b01 + c4);
        c[k] = *(const v4f*)(x + b10 + c4);
        d[k] = *(const v4f*)(x + b11 + c4);
    }
#pragma unroll
    for (int k = 0; k < 2; ++k) {
        const float wx = wxv[k], wy = wyv[k];
        const v4f top = a[k] * (1.0f - wx) + b[k] * wx;
        const v4f bot = c[k] * (1.0f - wx) + d[k] * wx;
        v4f res = top * (1.0f - wy) + bot * wy;
        if (!validv[k]) res = (v4f)0.0f;
        v4f* o = (v4f*)(out + (unsigned)(cell0 + k) * C + c4);
        __builtin_nontemporal_store(res, o);
    }
}

extern "C" void kernel_launch(void* const* d_in, const int* in_sizes, int n_in,
                              void* d_out, int out_size, void* d_ws, size_t ws_size,
                              hipStream_t stream)
{
    const float* x    = (const float*)d_in[0];
    const float* rois = (const float*)d_in[1];
    float* out = (float*)d_out;

    const size_t needed = WS_INTS * sizeof(int);
    if (ws_size >= needed) {
        int* cnt   = (int*)d_ws;
        int* lists = cnt + BANDS * CNT_STRIDE;
        zero_counts<<<1, 256, 0, stream>>>(cnt);
        bin_cells<<<(NCELL + 255) / 256, 256, 0, stream>>>(rois, cnt, lists);
        roi_pool_binned<<<P2_BLOCKS, 256, 0, stream>>>(x, rois, out, cnt, lists);
    } else {
        roi_pool_plain<<<NCELL / 8, 256, 0, stream>>>(x, rois, out);
    }
}